// Round 3
// baseline (1726.793 us; speedup 1.0000x reference)
//
#include <hip/hip_runtime.h>
#include <math.h>

#define HW 65536

// ---------- tables: cosT/sinT[k][x] (16x256) and ET[j][x] (32x256, j=2k:cos, j=2k+1:-sin) ----------
__global__ __launch_bounds__(256) void k_tables(float* __restrict__ cosT, float* __restrict__ sinT,
                                                float* __restrict__ ET) {
  int idx = blockIdx.x * 256 + threadIdx.x;   // 48*256 = 12288 >= 4096 + 8192
  const float w = 0.0245436926061702596f;     // 2*pi/256
  if (idx < 4096) {
    int k = idx >> 8, xx = idx & 255;
    int t = (k * xx) & 255;
    float ang = (float)t * w;
    cosT[idx] = cosf(ang);
    sinT[idx] = sinf(ang);
  } else if (idx < 12288) {
    int e = idx - 4096;
    int j = e >> 8, xx = e & 255;
    int k = j >> 1;
    int t = (k * xx) & 255;
    float ang = (float)t * w;
    ET[e] = (j & 1) ? -sinf(ang) : cosf(ang);
  }
}

// ---------- fc0: (B,3,H,W) -> (B,64,H,W) ----------
__global__ __launch_bounds__(256) void k_fc0(const float* __restrict__ x, const float* __restrict__ w,
                                             const float* __restrict__ b, float* __restrict__ h) {
  int bid = blockIdx.x;                 // 1024 = B*H
  int bb = bid >> 8, y = bid & 255;
  int tx = threadIdx.x;
  __shared__ float ws[192];
  __shared__ float bs[64];
  if (tx < 192) ws[tx] = w[tx];
  if (tx < 64) bs[tx] = b[tx];
  __syncthreads();
  const float* xp = x + ((bb * 3) * 256 + y) * 256 + tx;
  float v0 = xp[0], v1 = xp[HW], v2 = xp[2 * HW];
  float* hp = h + ((bb * 64) * 256 + y) * 256 + tx;
#pragma unroll 4
  for (int o = 0; o < 64; ++o) {
    hp[o * HW] = bs[o] + ws[o * 3] * v0 + ws[o * 3 + 1] * v1 + ws[o * 3 + 2] * v2;
  }
}

// ---------- F1 as register-tiled GEMM: A[r][k] (float2), r = (b*64+c)*256+y ----------
__global__ __launch_bounds__(256) void k_f1(const float* __restrict__ h, const float* __restrict__ ET,
                                            float2* __restrict__ A) {
  __shared__ float es[32 * 260];   // E^T padded
  __shared__ float hs[256 * 36];   // 256 rows x 32 k-chunk, padded stride 36
  int tid = threadIdx.x;
  int tm = tid & 31, tn = tid >> 5;
  int r0 = blockIdx.x * 256;
  int base = r0 * 256;
#pragma unroll
  for (int rep = 0; rep < 32; ++rep) {
    int flat = rep * 256 + tid;
    es[(flat >> 8) * 260 + (flat & 255)] = ET[flat];
  }
  float4 st[8];
  {
    const float4* hp = (const float4*)(h + base);
#pragma unroll
    for (int q = 0; q < 8; ++q) {
      int flat = q * 256 + tid;
      st[q] = hp[(flat >> 3) * 64 + (flat & 7)];
    }
  }
  float acc[8][4];
#pragma unroll
  for (int i = 0; i < 8; ++i)
#pragma unroll
    for (int p = 0; p < 4; ++p) acc[i][p] = 0.f;

  for (int xc = 0; xc < 8; ++xc) {
    __syncthreads();
#pragma unroll
    for (int q = 0; q < 8; ++q) {
      int flat = q * 256 + tid;
      *(float4*)&hs[(flat >> 3) * 36 + (flat & 7) * 4] = st[q];
    }
    __syncthreads();
    if (xc < 7) {
      const float4* hp = (const float4*)(h + base) + (xc + 1) * 8;
#pragma unroll
      for (int q = 0; q < 8; ++q) {
        int flat = q * 256 + tid;
        st[q] = hp[(flat >> 3) * 64 + (flat & 7)];
      }
    }
    int xbase = xc * 32;
#pragma unroll
    for (int kk = 0; kk < 32; kk += 4) {
      float4 e0 = *(const float4*)&es[(tn * 4 + 0) * 260 + xbase + kk];
      float4 e1 = *(const float4*)&es[(tn * 4 + 1) * 260 + xbase + kk];
      float4 e2 = *(const float4*)&es[(tn * 4 + 2) * 260 + xbase + kk];
      float4 e3 = *(const float4*)&es[(tn * 4 + 3) * 260 + xbase + kk];
#pragma unroll
      for (int i = 0; i < 8; ++i) {
        float4 hv = *(const float4*)&hs[(tm + 32 * i) * 36 + kk];
        acc[i][0] += hv.x * e0.x + hv.y * e0.y + hv.z * e0.z + hv.w * e0.w;
        acc[i][1] += hv.x * e1.x + hv.y * e1.y + hv.z * e1.z + hv.w * e1.w;
        acc[i][2] += hv.x * e2.x + hv.y * e2.y + hv.z * e2.z + hv.w * e2.w;
        acc[i][3] += hv.x * e3.x + hv.y * e3.y + hv.z * e3.z + hv.w * e3.w;
      }
    }
  }
#pragma unroll
  for (int i = 0; i < 8; ++i) {
    int r = r0 + tm + 32 * i;
    *(float4*)&A[r * 16 + tn * 2] = make_float4(acc[i][0], acc[i][1], acc[i][2], acc[i][3]);
  }
}

// ---------- F2: col DFT over y, LDS-staged ----------
__global__ __launch_bounds__(256) void k_f2(const float2* __restrict__ A, const float* __restrict__ cosT,
                                            const float* __restrict__ sinT, float2* __restrict__ X) {
  int plane = blockIdx.x;               // 256 = B*C
  int tid = threadIdx.x;
  __shared__ float2 As[256 * 16];       // 32 KB
  __shared__ float ct[16 * 257];
  __shared__ float stt[16 * 257];
  const float2* Ap = A + plane * 4096;
#pragma unroll
  for (int rep = 0; rep < 16; ++rep) {
    int flat = rep * 256 + tid;
    As[flat] = Ap[flat];
  }
#pragma unroll
  for (int rep = 0; rep < 16; ++rep) {
    int flat = rep * 256 + tid;
    int ky = flat >> 8, y = flat & 255;
    ct[ky * 257 + y] = cosT[flat];
    stt[ky * 257 + y] = sinT[flat];
  }
  __syncthreads();
  int ky = tid >> 4, kx = tid & 15;
  float xr = 0.f, xi = 0.f;
#pragma unroll 4
  for (int y = 0; y < 256; ++y) {
    float2 a = As[y * 16 + kx];
    float c = ct[ky * 257 + y], s = stt[ky * 257 + y];
    xr += c * a.x + s * a.y;
    xi += c * a.y - s * a.x;
  }
  X[plane * 256 + tid] = make_float2(xr, xi);
}

// ---------- MIX: Y[b,o,m] = sum_c X[b,c,m] * (wr+i wi)[c,o,m], c split 4-way in-block ----------
__global__ __launch_bounds__(256) void k_mix(const float2* __restrict__ X, const float* __restrict__ wr,
                                             const float* __restrict__ wi, float2* __restrict__ Y) {
  int o = blockIdx.x >> 2;              // 64 o * 4 m-chunks
  int mc = blockIdx.x & 3;
  int tid = threadIdx.x;
  int cg = tid >> 6, m2 = tid & 63;
  int m = mc * 64 + m2;
  float yr[4] = {0.f, 0.f, 0.f, 0.f}, yi[4] = {0.f, 0.f, 0.f, 0.f};
#pragma unroll 4
  for (int cc = 0; cc < 16; ++cc) {
    int c = cg * 16 + cc;
    float r = wr[(c * 64 + o) * 256 + m];
    float im = wi[(c * 64 + o) * 256 + m];
#pragma unroll
    for (int b = 0; b < 4; ++b) {
      float2 xv = X[(b * 64 + c) * 256 + m];
      yr[b] += xv.x * r - xv.y * im;
      yi[b] += xv.x * im + xv.y * r;
    }
  }
  __shared__ float2 red[1024];
#pragma unroll
  for (int b = 0; b < 4; ++b) red[cg * 256 + b * 64 + m2] = make_float2(yr[b], yi[b]);
  __syncthreads();
  int b = tid >> 6;
  float sx = 0.f, sy = 0.f;
#pragma unroll
  for (int g2 = 0; g2 < 4; ++g2) {
    float2 v = red[g2 * 256 + b * 64 + m2];
    sx += v.x; sy += v.y;
  }
  Y[(b * 64 + o) * 256 + m] = make_float2(sx, sy);
}

// ---------- INV1: g[b,o,y,kx] = sum_ky Y[b,o,ky,kx] e^{+2pi i ky y/256}, scaled ----------
__global__ __launch_bounds__(256) void k_inv1(const float2* __restrict__ Y, const float* __restrict__ cosT,
                                              const float* __restrict__ sinT, float2* __restrict__ g) {
  int plane = blockIdx.x;               // 256 = B*O
  int y = threadIdx.x;
  __shared__ float2 Ys[256];
  Ys[threadIdx.x] = Y[plane * 256 + threadIdx.x];
  __syncthreads();
  float gr[16], gi[16];
#pragma unroll
  for (int k = 0; k < 16; ++k) { gr[k] = 0.f; gi[k] = 0.f; }
  for (int ky = 0; ky < 16; ++ky) {
    float c = cosT[ky * 256 + y], s = sinT[ky * 256 + y];
#pragma unroll
    for (int kx = 0; kx < 16; ++kx) {
      float2 v = Ys[ky * 16 + kx];
      gr[kx] += c * v.x - s * v.y;
      gi[kx] += c * v.y + s * v.x;
    }
  }
  float2* gp = g + (plane * 256 + y) * 16;
  const float sc = 1.0f / 65536.0f;
#pragma unroll
  for (int kx = 0; kx < 16; ++kx) {
    float m = (kx == 0) ? sc : 2.0f * sc;
    gp[kx] = make_float2(gr[kx] * m, gi[kx] * m);
  }
}

// ---------- K_LAYER: hout = GELU( invDFT_x(g) + conv1x1(h, ww) + wb ) ----------
// block = (b, y, x-quarter). 64 lanes = 64 consecutive x. wave -> o-group (16 o).
// Weights & g are wave-uniform -> SGPR (s_load) path. h column kept in VGPRs. No LDS.
__global__ __launch_bounds__(256) void k_layer(const float* __restrict__ h, const float* __restrict__ g,
                                               const float* __restrict__ ww, const float* __restrict__ wb,
                                               const float* __restrict__ cosT, const float* __restrict__ sinT,
                                               float* __restrict__ hout) {
  int bid = blockIdx.x;                 // 4096 = b*1024 + y*4 + xq
  int xq = bid & 3, y = (bid >> 2) & 255, b = bid >> 10;
  int tid = threadIdx.x;
  int lane = tid & 63;
  int o0 = __builtin_amdgcn_readfirstlane((tid >> 6) * 16);
  int x = xq * 64 + lane;

  const float* hp = h + ((b * 64) * 256 + y) * 256 + x;
  float hv[64];
#pragma unroll
  for (int c = 0; c < 64; ++c) hv[c] = hp[c * HW];

  float tcx[16], tsx[16];
#pragma unroll
  for (int kx = 0; kx < 16; ++kx) {
    tcx[kx] = cosT[kx * 256 + x];
    tsx[kx] = sinT[kx * 256 + x];
  }

  const float* gb = g + ((size_t)(b * 64 + o0) * 256 + y) * 32;   // per-o stride 8192
#pragma unroll 2
  for (int i = 0; i < 16; ++i) {
    const float* wrow = ww + (o0 + i) * 64;   // wave-uniform -> s_load rows
    float a0 = 0.f, a1 = 0.f, a2 = 0.f, a3 = 0.f;
#pragma unroll
    for (int c = 0; c < 64; c += 4) {
      a0 += wrow[c] * hv[c];
      a1 += wrow[c + 1] * hv[c + 1];
      a2 += wrow[c + 2] * hv[c + 2];
      a3 += wrow[c + 3] * hv[c + 3];
    }
    float a = (a0 + a1) + (a2 + a3);
    const float* gp = gb + i * 8192;          // wave-uniform
#pragma unroll
    for (int kx = 0; kx < 16; ++kx) {
      a += gp[2 * kx] * tcx[kx] - gp[2 * kx + 1] * tsx[kx];
    }
    float v = a + wb[o0 + i];
    float r = 0.5f * v * (1.0f + erff(v * 0.70710678118654752f));
    hout[((b * 64 + o0 + i) * 256 + y) * 256 + x] = r;
  }
}

// ---------- K_FINAL: out = fc2( GELU( fc1(h) ) ) ----------
// block = (b, y, x-quarter). wave -> j-group (32 j). w1 rows via s_load; h column in VGPRs.
__global__ __launch_bounds__(256) void k_final(const float* __restrict__ h, const float* __restrict__ w1,
                                               const float* __restrict__ b1, const float* __restrict__ w2,
                                               const float* __restrict__ b2, float* __restrict__ out) {
  int bid = blockIdx.x;                 // 4096 = b*1024 + y*4 + xq
  int xq = bid & 3, y = (bid >> 2) & 255, b = bid >> 10;
  int tid = threadIdx.x;
  int lane = tid & 63, wave = tid >> 6;
  int j0 = __builtin_amdgcn_readfirstlane(wave * 32);
  int x = xq * 64 + lane;

  const float* hp = h + ((b * 64) * 256 + y) * 256 + x;
  float hv[64];
#pragma unroll
  for (int c = 0; c < 64; ++c) hv[c] = hp[c * HW];

  float p = 0.f;
#pragma unroll 2
  for (int i = 0; i < 32; ++i) {
    int j = j0 + i;
    const float* wrow = w1 + j * 64;          // wave-uniform -> s_load rows
    float a0 = 0.f, a1 = 0.f, a2 = 0.f, a3 = 0.f;
#pragma unroll
    for (int c = 0; c < 64; c += 4) {
      a0 += wrow[c] * hv[c];
      a1 += wrow[c + 1] * hv[c + 1];
      a2 += wrow[c + 2] * hv[c + 2];
      a3 += wrow[c + 3] * hv[c + 3];
    }
    float v = (a0 + a1) + (a2 + a3) + b1[j];
    float r = 0.5f * v * (1.0f + erff(v * 0.70710678118654752f));
    p += w2[j] * r;
  }

  __shared__ float red[4][64];
  red[wave][lane] = p;
  __syncthreads();
  if (wave == 0) {
    float s = red[0][lane] + red[1][lane] + red[2][lane] + red[3][lane];
    out[(b * 256 + y) * 256 + x] = s + b2[0];
  }
}

extern "C" void kernel_launch(void* const* d_in, const int* in_sizes, int n_in,
                              void* d_out, int out_size, void* d_ws, size_t ws_size,
                              hipStream_t stream) {
  const float* x       = (const float*)d_in[0];
  const float* fc0_w   = (const float*)d_in[1];
  const float* fc0_b   = (const float*)d_in[2];
  const float* spec_wr = (const float*)d_in[3];
  const float* spec_wi = (const float*)d_in[4];
  const float* w_w     = (const float*)d_in[5];
  const float* w_b     = (const float*)d_in[6];
  const float* fc1_w   = (const float*)d_in[7];
  const float* fc1_b   = (const float*)d_in[8];
  const float* fc2_w   = (const float*)d_in[9];
  const float* fc2_b   = (const float*)d_in[10];
  float* out = (float*)d_out;

  char* ws = (char*)d_ws;
  float*  h0   = (float*)ws;                               // 67108864 B
  float*  h1   = (float*)(ws + 67108864);                  // 67108864 B
  float2* A    = (float2*)(ws + 134217728);                // 8388608 B
  float*  g    = (float*)(ws + 142606336);                 // 8388608 B
  float2* X    = (float2*)(ws + 150994944);                // 524288 B
  float2* Y    = (float2*)(ws + 151519232);                // 524288 B
  float*  cosT = (float*)(ws + 152043520);                 // 16384 B
  float*  sinT = cosT + 4096;                              // 16384 B
  float*  ET   = sinT + 4096;                              // 32768 B

  k_tables<<<48, 256, 0, stream>>>(cosT, sinT, ET);
  k_fc0<<<1024, 256, 0, stream>>>(x, fc0_w, fc0_b, h0);
  float* hc = h0; float* hn = h1;
  for (int l = 0; l < 4; ++l) {
    k_f1<<<256, 256, 0, stream>>>(hc, ET, A);
    k_f2<<<256, 256, 0, stream>>>(A, cosT, sinT, X);
    k_mix<<<256, 256, 0, stream>>>(X, spec_wr + (size_t)l * 1048576, spec_wi + (size_t)l * 1048576, Y);
    k_inv1<<<256, 256, 0, stream>>>(Y, cosT, sinT, (float2*)g);
    k_layer<<<4096, 256, 0, stream>>>(hc, g, w_w + l * 4096, w_b + l * 64, cosT, sinT, hn);
    float* t = hc; hc = hn; hn = t;
  }
  k_final<<<4096, 256, 0, stream>>>(hc, fc1_w, fc1_b, fc2_w, fc2_b, out);
}

// Round 4
// 1098.521 us; speedup vs baseline: 1.5719x; 1.5719x over previous
//
#include <hip/hip_runtime.h>
#include <math.h>

#define HW 65536

// ---------- tables: cosT/sinT[k][x] (16x256) and ET[j][x] (32x256, j=2k:cos, j=2k+1:-sin) ----------
__global__ __launch_bounds__(256) void k_tables(float* __restrict__ cosT, float* __restrict__ sinT,
                                                float* __restrict__ ET) {
  int idx = blockIdx.x * 256 + threadIdx.x;   // 48*256 = 12288 >= 4096 + 8192
  const float w = 0.0245436926061702596f;     // 2*pi/256
  if (idx < 4096) {
    int k = idx >> 8, xx = idx & 255;
    int t = (k * xx) & 255;
    float ang = (float)t * w;
    cosT[idx] = cosf(ang);
    sinT[idx] = sinf(ang);
  } else if (idx < 12288) {
    int e = idx - 4096;
    int j = e >> 8, xx = e & 255;
    int k = j >> 1;
    int t = (k * xx) & 255;
    float ang = (float)t * w;
    ET[e] = (j & 1) ? -sinf(ang) : cosf(ang);
  }
}

// ---------- fc0: (B,3,H,W) -> (B,64,H,W) ----------
__global__ __launch_bounds__(256) void k_fc0(const float* __restrict__ x, const float* __restrict__ w,
                                             const float* __restrict__ b, float* __restrict__ h) {
  int bid = blockIdx.x;                 // 1024 = B*H
  int bb = bid >> 8, y = bid & 255;
  int tx = threadIdx.x;
  __shared__ float ws[192];
  __shared__ float bs[64];
  if (tx < 192) ws[tx] = w[tx];
  if (tx < 64) bs[tx] = b[tx];
  __syncthreads();
  const float* xp = x + ((bb * 3) * 256 + y) * 256 + tx;
  float v0 = xp[0], v1 = xp[HW], v2 = xp[2 * HW];
  float* hp = h + ((bb * 64) * 256 + y) * 256 + tx;
#pragma unroll 4
  for (int o = 0; o < 64; ++o) {
    hp[o * HW] = bs[o] + ws[o * 3] * v0 + ws[o * 3 + 1] * v1 + ws[o * 3 + 2] * v2;
  }
}

// ---------- F1 as register-tiled GEMM: A[r][k] (float2), r = (b*64+c)*256+y ----------
__global__ __launch_bounds__(256) void k_f1(const float* __restrict__ h, const float* __restrict__ ET,
                                            float2* __restrict__ A) {
  __shared__ float es[32 * 260];   // E^T padded
  __shared__ float hs[256 * 36];   // 256 rows x 32 k-chunk, padded stride 36
  int tid = threadIdx.x;
  int tm = tid & 31, tn = tid >> 5;
  int r0 = blockIdx.x * 256;
  int base = r0 * 256;
#pragma unroll
  for (int rep = 0; rep < 32; ++rep) {
    int flat = rep * 256 + tid;
    es[(flat >> 8) * 260 + (flat & 255)] = ET[flat];
  }
  float4 st[8];
  {
    const float4* hp = (const float4*)(h + base);
#pragma unroll
    for (int q = 0; q < 8; ++q) {
      int flat = q * 256 + tid;
      st[q] = hp[(flat >> 3) * 64 + (flat & 7)];
    }
  }
  float acc[8][4];
#pragma unroll
  for (int i = 0; i < 8; ++i)
#pragma unroll
    for (int p = 0; p < 4; ++p) acc[i][p] = 0.f;

  for (int xc = 0; xc < 8; ++xc) {
    __syncthreads();
#pragma unroll
    for (int q = 0; q < 8; ++q) {
      int flat = q * 256 + tid;
      *(float4*)&hs[(flat >> 3) * 36 + (flat & 7) * 4] = st[q];
    }
    __syncthreads();
    if (xc < 7) {
      const float4* hp = (const float4*)(h + base) + (xc + 1) * 8;
#pragma unroll
      for (int q = 0; q < 8; ++q) {
        int flat = q * 256 + tid;
        st[q] = hp[(flat >> 3) * 64 + (flat & 7)];
      }
    }
    int xbase = xc * 32;
#pragma unroll
    for (int kk = 0; kk < 32; kk += 4) {
      float4 e0 = *(const float4*)&es[(tn * 4 + 0) * 260 + xbase + kk];
      float4 e1 = *(const float4*)&es[(tn * 4 + 1) * 260 + xbase + kk];
      float4 e2 = *(const float4*)&es[(tn * 4 + 2) * 260 + xbase + kk];
      float4 e3 = *(const float4*)&es[(tn * 4 + 3) * 260 + xbase + kk];
#pragma unroll
      for (int i = 0; i < 8; ++i) {
        float4 hv = *(const float4*)&hs[(tm + 32 * i) * 36 + kk];
        acc[i][0] += hv.x * e0.x + hv.y * e0.y + hv.z * e0.z + hv.w * e0.w;
        acc[i][1] += hv.x * e1.x + hv.y * e1.y + hv.z * e1.z + hv.w * e1.w;
        acc[i][2] += hv.x * e2.x + hv.y * e2.y + hv.z * e2.z + hv.w * e2.w;
        acc[i][3] += hv.x * e3.x + hv.y * e3.y + hv.z * e3.z + hv.w * e3.w;
      }
    }
  }
#pragma unroll
  for (int i = 0; i < 8; ++i) {
    int r = r0 + tm + 32 * i;
    *(float4*)&A[r * 16 + tn * 2] = make_float4(acc[i][0], acc[i][1], acc[i][2], acc[i][3]);
  }
}

// ---------- F2: col DFT over y, LDS-staged ----------
__global__ __launch_bounds__(256) void k_f2(const float2* __restrict__ A, const float* __restrict__ cosT,
                                            const float* __restrict__ sinT, float2* __restrict__ X) {
  int plane = blockIdx.x;               // 256 = B*C
  int tid = threadIdx.x;
  __shared__ float2 As[256 * 16];       // 32 KB
  __shared__ float ct[16 * 257];
  __shared__ float stt[16 * 257];
  const float2* Ap = A + plane * 4096;
#pragma unroll
  for (int rep = 0; rep < 16; ++rep) {
    int flat = rep * 256 + tid;
    As[flat] = Ap[flat];
  }
#pragma unroll
  for (int rep = 0; rep < 16; ++rep) {
    int flat = rep * 256 + tid;
    int ky = flat >> 8, y = flat & 255;
    ct[ky * 257 + y] = cosT[flat];
    stt[ky * 257 + y] = sinT[flat];
  }
  __syncthreads();
  int ky = tid >> 4, kx = tid & 15;
  float xr = 0.f, xi = 0.f;
#pragma unroll 4
  for (int y = 0; y < 256; ++y) {
    float2 a = As[y * 16 + kx];
    float c = ct[ky * 257 + y], s = stt[ky * 257 + y];
    xr += c * a.x + s * a.y;
    xi += c * a.y - s * a.x;
  }
  X[plane * 256 + tid] = make_float2(xr, xi);
}

// ---------- MIX: Y[b,o,m] = sum_c X[b,c,m] * (wr+i wi)[c,o,m], c split 4-way in-block ----------
__global__ __launch_bounds__(256) void k_mix(const float2* __restrict__ X, const float* __restrict__ wr,
                                             const float* __restrict__ wi, float2* __restrict__ Y) {
  int o = blockIdx.x >> 2;              // 64 o * 4 m-chunks
  int mc = blockIdx.x & 3;
  int tid = threadIdx.x;
  int cg = tid >> 6, m2 = tid & 63;
  int m = mc * 64 + m2;
  float yr[4] = {0.f, 0.f, 0.f, 0.f}, yi[4] = {0.f, 0.f, 0.f, 0.f};
#pragma unroll 4
  for (int cc = 0; cc < 16; ++cc) {
    int c = cg * 16 + cc;
    float r = wr[(c * 64 + o) * 256 + m];
    float im = wi[(c * 64 + o) * 256 + m];
#pragma unroll
    for (int b = 0; b < 4; ++b) {
      float2 xv = X[(b * 64 + c) * 256 + m];
      yr[b] += xv.x * r - xv.y * im;
      yi[b] += xv.x * im + xv.y * r;
    }
  }
  __shared__ float2 red[1024];
#pragma unroll
  for (int b = 0; b < 4; ++b) red[cg * 256 + b * 64 + m2] = make_float2(yr[b], yi[b]);
  __syncthreads();
  int b = tid >> 6;
  float sx = 0.f, sy = 0.f;
#pragma unroll
  for (int g2 = 0; g2 < 4; ++g2) {
    float2 v = red[g2 * 256 + b * 64 + m2];
    sx += v.x; sy += v.y;
  }
  Y[(b * 64 + o) * 256 + m] = make_float2(sx, sy);
}

// ---------- INV1: g[b,o,y,kx] = sum_ky Y[b,o,ky,kx] e^{+2pi i ky y/256}, scaled ----------
__global__ __launch_bounds__(256) void k_inv1(const float2* __restrict__ Y, const float* __restrict__ cosT,
                                              const float* __restrict__ sinT, float2* __restrict__ g) {
  int plane = blockIdx.x;               // 256 = B*O
  int y = threadIdx.x;
  __shared__ float2 Ys[256];
  Ys[threadIdx.x] = Y[plane * 256 + threadIdx.x];
  __syncthreads();
  float gr[16], gi[16];
#pragma unroll
  for (int k = 0; k < 16; ++k) { gr[k] = 0.f; gi[k] = 0.f; }
  for (int ky = 0; ky < 16; ++ky) {
    float c = cosT[ky * 256 + y], s = sinT[ky * 256 + y];
#pragma unroll
    for (int kx = 0; kx < 16; ++kx) {
      float2 v = Ys[ky * 16 + kx];
      gr[kx] += c * v.x - s * v.y;
      gi[kx] += c * v.y + s * v.x;
    }
  }
  float2* gp = g + (plane * 256 + y) * 16;
  const float sc = 1.0f / 65536.0f;
#pragma unroll
  for (int kx = 0; kx < 16; ++kx) {
    float m = (kx == 0) ? sc : 2.0f * sc;
    gp[kx] = make_float2(gr[kx] * m, gi[kx] * m);
  }
}

// ---------- K_LAYER: hout = GELU( [W^T | g] x [h ; ET] + wb ) ----------
// Augmented K=96 GEMM per (b,y): rows 0-63 conv (A=W^T, B=h), rows 64-95 spectral
// (A=g(b,:,y) re/im, B=ET). Thread tile 8o x (4+4)x; stride-65 LDS (conflict-free).
__global__ __launch_bounds__(256) void k_layer(const float* __restrict__ h, const float* __restrict__ g,
                                               const float* __restrict__ ww, const float* __restrict__ wb,
                                               const float* __restrict__ ET, float* __restrict__ hout) {
  int bid = blockIdx.x;                 // 1024 = b*256 + y
  int b = bid >> 8, y = bid & 255;
  int tid = threadIdx.x;
  int to = tid >> 5, tx = tid & 31;
  int o0 = to * 8;
  int xlo = tx * 4, xhi = 128 + tx * 4;
  __shared__ float As[96 * 65];         // 24.4 KB, stride 65 (== 1 mod 32)
  __shared__ float Bs[16 * 256];        // 16 KB

  // stage A: W^T (rows 0-63), then g (rows 64-95). 2-way conflicts max (free).
#pragma unroll
  for (int p = 0; p < 16; ++p) {
    int flat = p * 256 + tid;
    As[(flat & 63) * 65 + (flat >> 6)] = ww[flat];
  }
#pragma unroll
  for (int p = 0; p < 8; ++p) {
    int flat = p * 256 + tid;
    As[(64 + (flat & 31)) * 65 + (flat >> 5)] =
        g[(size_t)(b * 64 + (flat >> 5)) * 8192 + y * 32 + (flat & 31)];
  }

  const float4* hb = (const float4*)(h + (size_t)b * 64 * HW + y * 256);
  const float4* et4 = (const float4*)ET;

  float acc[8][8];
#pragma unroll
  for (int i = 0; i < 8; ++i)
#pragma unroll
    for (int j = 0; j < 8; ++j) acc[i][j] = 0.f;

  float4 st[4];
#pragma unroll
  for (int q = 0; q < 4; ++q) {
    int flat = q * 256 + tid;
    st[q] = hb[(size_t)(flat >> 6) * 16384 + (flat & 63)];
  }

  for (int ch = 0; ch < 6; ++ch) {
    __syncthreads();
#pragma unroll
    for (int q = 0; q < 4; ++q) {
      int flat = q * 256 + tid;
      *(float4*)&Bs[flat * 4] = st[q];
    }
    __syncthreads();
    if (ch < 5) {
      int nc = ch + 1;
#pragma unroll
      for (int q = 0; q < 4; ++q) {
        int flat = q * 256 + tid;
        int row = flat >> 6, xi = flat & 63;
        st[q] = (nc < 4) ? hb[(size_t)(nc * 16 + row) * 16384 + xi]
                         : et4[((nc - 4) * 16 + row) * 64 + xi];
      }
    }
    int kb = ch * 16;
#pragma unroll
    for (int k = 0; k < 16; ++k) {
      const float* ar = &As[(kb + k) * 65 + o0];
      float4 a0 = *(const float4*)ar;
      float4 a1 = *(const float4*)(ar + 4);
      float4 b0 = *(const float4*)&Bs[k * 256 + xlo];
      float4 b1 = *(const float4*)&Bs[k * 256 + xhi];
      float av[8] = {a0.x, a0.y, a0.z, a0.w, a1.x, a1.y, a1.z, a1.w};
      float bv[8] = {b0.x, b0.y, b0.z, b0.w, b1.x, b1.y, b1.z, b1.w};
#pragma unroll
      for (int i = 0; i < 8; ++i)
#pragma unroll
        for (int j = 0; j < 8; ++j) acc[i][j] += av[i] * bv[j];
    }
  }
#pragma unroll
  for (int i = 0; i < 8; ++i) {
    int o = o0 + i;
    float bia = wb[o];
    float r[8];
#pragma unroll
    for (int j = 0; j < 8; ++j) {
      float v = acc[i][j] + bia;
      r[j] = 0.5f * v * (1.0f + erff(v * 0.70710678118654752f));
    }
    float* op = &hout[(size_t)(b * 64 + o) * HW + y * 256];
    *(float4*)(op + xlo) = make_float4(r[0], r[1], r[2], r[3]);
    *(float4*)(op + xhi) = make_float4(r[4], r[5], r[6], r[7]);
  }
}

// ---------- K_FINAL: out = fc2( GELU( fc1(h) ) ), same GEMM structure, j in 2 halves ----------
__global__ __launch_bounds__(256) void k_final(const float* __restrict__ h, const float* __restrict__ w1,
                                               const float* __restrict__ b1, const float* __restrict__ w2,
                                               const float* __restrict__ b2, float* __restrict__ out) {
  int bid = blockIdx.x;                 // 1024 = b*256 + y
  int b = bid >> 8, y = bid & 255;
  int tid = threadIdx.x;
  int to = tid >> 5, tx = tid & 31;
  int j0 = to * 8;
  int xlo = tx * 4, xhi = 128 + tx * 4;
  __shared__ float As[64 * 65];         // 16.6 KB
  __shared__ float Bs[16 * 256];        // 16 KB
  __shared__ float red[8 * 264];        // 8.4 KB

  const float4* hb = (const float4*)(h + (size_t)b * 64 * HW + y * 256);

  float p[8];
#pragma unroll
  for (int q = 0; q < 8; ++q) p[q] = 0.f;

  for (int jh = 0; jh < 2; ++jh) {
    if (jh) __syncthreads();            // protect As from previous half's readers
#pragma unroll
    for (int pq = 0; pq < 16; ++pq) {
      int flat = pq * 256 + tid;
      As[(flat & 63) * 65 + (flat >> 6)] = w1[(jh * 64 + (flat >> 6)) * 64 + (flat & 63)];
    }
    float acc[8][8];
#pragma unroll
    for (int i = 0; i < 8; ++i)
#pragma unroll
      for (int j = 0; j < 8; ++j) acc[i][j] = 0.f;

    float4 st[4];
#pragma unroll
    for (int q = 0; q < 4; ++q) {
      int flat = q * 256 + tid;
      st[q] = hb[(size_t)(flat >> 6) * 16384 + (flat & 63)];
    }
    for (int ch = 0; ch < 4; ++ch) {
      __syncthreads();
#pragma unroll
      for (int q = 0; q < 4; ++q) {
        int flat = q * 256 + tid;
        *(float4*)&Bs[flat * 4] = st[q];
      }
      __syncthreads();
      if (ch < 3) {
#pragma unroll
        for (int q = 0; q < 4; ++q) {
          int flat = q * 256 + tid;
          st[q] = hb[(size_t)((ch + 1) * 16 + (flat >> 6)) * 16384 + (flat & 63)];
        }
      }
      int kb = ch * 16;
#pragma unroll
      for (int k = 0; k < 16; ++k) {
        const float* ar = &As[(kb + k) * 65 + j0];
        float4 a0 = *(const float4*)ar;
        float4 a1 = *(const float4*)(ar + 4);
        float4 b0 = *(const float4*)&Bs[k * 256 + xlo];
        float4 b1 = *(const float4*)&Bs[k * 256 + xhi];
        float av[8] = {a0.x, a0.y, a0.z, a0.w, a1.x, a1.y, a1.z, a1.w};
        float bv[8] = {b0.x, b0.y, b0.z, b0.w, b1.x, b1.y, b1.z, b1.w};
#pragma unroll
        for (int i = 0; i < 8; ++i)
#pragma unroll
          for (int j = 0; j < 8; ++j) acc[i][j] += av[i] * bv[j];
      }
    }
#pragma unroll
    for (int i = 0; i < 8; ++i) {
      int j = jh * 64 + j0 + i;
      float bia = b1[j], f2 = w2[j];
#pragma unroll
      for (int q = 0; q < 8; ++q) {
        float v = acc[i][q] + bia;
        float r = 0.5f * v * (1.0f + erff(v * 0.70710678118654752f));
        p[q] += f2 * r;
      }
    }
  }
  *(float4*)&red[to * 264 + xlo] = make_float4(p[0], p[1], p[2], p[3]);
  *(float4*)&red[to * 264 + xhi] = make_float4(p[4], p[5], p[6], p[7]);
  __syncthreads();
  float s = 0.f;
#pragma unroll
  for (int t = 0; t < 8; ++t) s += red[t * 264 + tid];
  out[(b * 256 + y) * 256 + tid] = s + b2[0];
}

extern "C" void kernel_launch(void* const* d_in, const int* in_sizes, int n_in,
                              void* d_out, int out_size, void* d_ws, size_t ws_size,
                              hipStream_t stream) {
  const float* x       = (const float*)d_in[0];
  const float* fc0_w   = (const float*)d_in[1];
  const float* fc0_b   = (const float*)d_in[2];
  const float* spec_wr = (const float*)d_in[3];
  const float* spec_wi = (const float*)d_in[4];
  const float* w_w     = (const float*)d_in[5];
  const float* w_b     = (const float*)d_in[6];
  const float* fc1_w   = (const float*)d_in[7];
  const float* fc1_b   = (const float*)d_in[8];
  const float* fc2_w   = (const float*)d_in[9];
  const float* fc2_b   = (const float*)d_in[10];
  float* out = (float*)d_out;

  char* ws = (char*)d_ws;
  float*  h0   = (float*)ws;                               // 67108864 B
  float*  h1   = (float*)(ws + 67108864);                  // 67108864 B
  float2* A    = (float2*)(ws + 134217728);                // 8388608 B
  float*  g    = (float*)(ws + 142606336);                 // 8388608 B
  float2* X    = (float2*)(ws + 150994944);                // 524288 B
  float2* Y    = (float2*)(ws + 151519232);                // 524288 B
  float*  cosT = (float*)(ws + 152043520);                 // 16384 B
  float*  sinT = cosT + 4096;                              // 16384 B
  float*  ET   = sinT + 4096;                              // 32768 B

  k_tables<<<48, 256, 0, stream>>>(cosT, sinT, ET);
  k_fc0<<<1024, 256, 0, stream>>>(x, fc0_w, fc0_b, h0);
  float* hc = h0; float* hn = h1;
  for (int l = 0; l < 4; ++l) {
    k_f1<<<256, 256, 0, stream>>>(hc, ET, A);
    k_f2<<<256, 256, 0, stream>>>(A, cosT, sinT, X);
    k_mix<<<256, 256, 0, stream>>>(X, spec_wr + (size_t)l * 1048576, spec_wi + (size_t)l * 1048576, Y);
    k_inv1<<<256, 256, 0, stream>>>(Y, cosT, sinT, (float2*)g);
    k_layer<<<1024, 256, 0, stream>>>(hc, g, w_w + l * 4096, w_b + l * 64, ET, hn);
    float* t = hc; hc = hn; hn = t;
  }
  k_final<<<1024, 256, 0, stream>>>(hc, fc1_w, fc1_b, fc2_w, fc2_b, out);
}